// Round 2
// baseline (369.873 us; speedup 1.0000x reference)
//
#include <hip/hip_runtime.h>

#define B_    32
#define H_    640
#define W_    368
#define OH    634          // H - 6
#define OW    362          // W - 6
#define CHUNK 14           // output rows per wave (multiple of 7)
#define NSTRIPE 6          // ceil(362/64)
#define NCY   12           // ceil(ceil(634/14)/4) = ceil(46/4)
#define TOTAL_WAVES (NSTRIPE * NCY * B_ * 4)   // 9216

// d_ws layout (floats):
//   [0..31]  per-batch max of target (int-bits atomicMax; 0xAA poison is negative int, any
//            positive-float bits win, so no pre-zeroing needed)
//   [32..95] 64 scattered partial-sum slots (zeroed by k_max block 0)
//   [96]     wave-completion counter (uint, zeroed by k_max block 0)

__global__ __launch_bounds__(256) void k_max(const float* __restrict__ tgt,
                                             float* __restrict__ ws) {
    const int b   = blockIdx.x >> 5;           // 32 segments per batch
    const int seg = blockIdx.x & 31;
    // init scratch (runs fully before k_ssim by stream order)
    if (blockIdx.x == 0) {
        if (threadIdx.x < 64) ws[32 + threadIdx.x] = 0.0f;
        if (threadIdx.x == 64) ((unsigned*)ws)[96] = 0u;
    }
    const int perseg = (H_ * W_) / 32;         // 7360 floats
    const float4* p = (const float4*)(tgt + (size_t)b * (H_ * W_) + (size_t)seg * perseg);
    const int n4 = perseg / 4;                 // 1840
    float m = 0.0f;
    for (int i = threadIdx.x; i < n4; i += 256) {
        float4 v = p[i];
        m = fmaxf(m, fmaxf(fmaxf(v.x, v.y), fmaxf(v.z, v.w)));
    }
    #pragma unroll
    for (int off = 32; off; off >>= 1)
        m = fmaxf(m, __shfl_down(m, off, 64));
    __shared__ float sm[4];
    const int lane = threadIdx.x & 63, wv = threadIdx.x >> 6;
    if (lane == 0) sm[wv] = m;
    __syncthreads();
    if (threadIdx.x == 0) {
        m = fmaxf(fmaxf(sm[0], sm[1]), fmaxf(sm[2], sm[3]));
        atomicMax((int*)ws + b, __float_as_int(m));   // inputs >= 0
    }
}

__global__ __launch_bounds__(256) void k_ssim(const float* __restrict__ X,
                                              const float* __restrict__ Y,
                                              float* __restrict__ ws,
                                              float* __restrict__ out) {
    const int sx   = blockIdx.x;               // column stripe
    const int w    = threadIdx.x >> 6;         // wave within block
    const int lane = threadIdx.x & 63;
    const int b    = blockIdx.z;
    const int chunkIdx = blockIdx.y * 4 + w;   // 0..47 (46 valid)
    const int r0   = chunkIdx * CHUNK;
    const int c    = sx * 64 + lane;
    const int outRows = min(CHUNK, OH - r0);   // <=0 for invalid chunks
    const bool colOK = (c < OW);

    const float dr  = ws[b];
    float C1 = 0.01f * dr; C1 *= C1;
    float C2 = 0.03f * dr; C2 *= C2;
    const float c1s = C1 * 2401.0f;            // C1 * 49^2 (scaled-domain constants)
    const float c2s = C2 * 2401.0f;
    const float covn2 = 2.0f * (49.0f / 48.0f);
    const float covn  = 49.0f / 48.0f;

    const float* xb = X + (size_t)b * (H_ * W_);
    const float* yb = Y + (size_t)b * (H_ * W_);

    float acc = 0.0f;

    if (colOK && outRows > 0) {
        float rx[7], ry[7], rxx[7], ryy[7], rxy[7];
        float tx = 0, ty = 0, txx = 0, tyy = 0, txy = 0;

        #pragma unroll
        for (int p = 0; p < 6; ++p) {          // prime 6 halo rows
            const float* xr = xb + (size_t)(r0 + p) * W_ + c;
            const float* yr = yb + (size_t)(r0 + p) * W_ + c;
            float hx = 0, hy = 0, hxx = 0, hyy = 0, hxy = 0;
            #pragma unroll
            for (int k = 0; k < 7; ++k) {
                float xv = xr[k], yv = yr[k];
                hx += xv; hy += yv;
                hxx = fmaf(xv, xv, hxx);
                hyy = fmaf(yv, yv, hyy);
                hxy = fmaf(xv, yv, hxy);
            }
            rx[p] = hx; ry[p] = hy; rxx[p] = hxx; ryy[p] = hyy; rxy[p] = hxy;
            tx += hx; ty += hy; txx += hxx; tyy += hyy; txy += hxy;
        }

        for (int ii = 0; ii < outRows; ii += 7) {
            #pragma unroll
            for (int p = 0; p < 7; ++p) {      // ring slots compile-time
                const int i = ii + p;
                if (i >= outRows) break;       // wave-uniform
                const float* xr = xb + (size_t)(r0 + i + 6) * W_ + c;
                const float* yr = yb + (size_t)(r0 + i + 6) * W_ + c;
                float hx = 0, hy = 0, hxx = 0, hyy = 0, hxy = 0;
                #pragma unroll
                for (int k = 0; k < 7; ++k) {
                    float xv = xr[k], yv = yr[k];
                    hx += xv; hy += yv;
                    hxx = fmaf(xv, xv, hxx);
                    hyy = fmaf(yv, yv, hyy);
                    hxy = fmaf(xv, yv, hxy);
                }
                tx += hx; ty += hy; txx += hxx; tyy += hyy; txy += hxy;

                // scaled-domain SSIM: all u* scales cancel in the ratio
                const float pxy = tx * ty;
                const float A1  = fmaf(pxy, 2.0f, c1s);            // 2*tx*ty + C1*49^2
                const float s2  = fmaf(tx, tx, ty * ty);           // tx^2 + ty^2
                const float B1  = s2 + c1s;
                const float mxy = fmaf(49.0f, txy, -pxy);          // 49*txy - tx*ty
                const float A2  = fmaf(covn2, mxy, c2s);
                const float vs  = fmaf(49.0f, txx + tyy, -s2);     // 49*(txx+tyy) - (tx^2+ty^2)
                const float B2  = fmaf(covn, vs, c2s);
                acc = fmaf(A1 * A2, __builtin_amdgcn_rcpf(B1 * B2), acc);

                tx -= rx[p]; ty -= ry[p]; txx -= rxx[p]; tyy -= ryy[p]; txy -= rxy[p];
                const int sn = (p + 6) % 7;
                rx[sn] = hx; ry[sn] = hy; rxx[sn] = hxx; ryy[sn] = hyy; rxy[sn] = hxy;
            }
        }
    }

    // per-wave reduction (no __syncthreads needed; no shared mem)
    #pragma unroll
    for (int off = 32; off; off >>= 1)
        acc += __shfl_down(acc, off, 64);

    if (lane == 0) {
        const int gw = ((b * NCY + blockIdx.y) * NSTRIPE + sx) * 4 + w;   // global wave id
        float* slots = ws + 32;
        atomicAdd(&slots[gw & 63], acc);
        __threadfence();
        unsigned old = atomicAdd((unsigned*)ws + 96, 1u);
        if (old == TOTAL_WAVES - 1) {          // last wave finalizes
            float s = 0.0f;
            #pragma unroll
            for (int i = 0; i < 64; ++i)
                s += atomicAdd(&slots[i], 0.0f);   // coherent read
            out[0] = 1.0f - s * (1.0f / (32.0f * 634.0f * 362.0f));
        }
    }
}

extern "C" void kernel_launch(void* const* d_in, const int* in_sizes, int n_in,
                              void* d_out, int out_size, void* d_ws, size_t ws_size,
                              hipStream_t stream) {
    const float* X = (const float*)d_in[0];   // 'output'
    const float* Y = (const float*)d_in[1];   // 'target'
    float* ws = (float*)d_ws;

    k_max<<<dim3(1024), dim3(256), 0, stream>>>(Y, ws);
    k_ssim<<<dim3(NSTRIPE, NCY, B_), dim3(256), 0, stream>>>(X, Y, ws, (float*)d_out);
}

// Round 3
// 129.461 us; speedup vs baseline: 2.8570x; 2.8570x over previous
//
#include <hip/hip_runtime.h>

#define B_    32
#define H_    640
#define W_    368
#define OH    634          // H - 6
#define OW    362          // W - 6
#define CHUNK 14           // output rows per wave (multiple of 7)
#define NSTRIPE 6          // ceil(362/64)
#define NCY   12           // 48 chunk-slots (46 valid)

// d_ws layout (floats):
//   [0..31]     per-batch max of target (int-bits atomicMax; 0xAA poison is a negative
//               int, any positive-float bits win, so no pre-zeroing needed)
//   [64..1087]  64 partial-sum slots, padded to 16 floats (64 B) each; zeroed by k_max blk 0
#define SLOT0 64
#define SLOTSTRIDE 16

__global__ __launch_bounds__(256) void k_max(const float* __restrict__ tgt,
                                             float* __restrict__ ws) {
    if (blockIdx.x == 0) {                     // zero the slot array (k_ssim runs after, stream order)
        for (int i = threadIdx.x; i < 64 * SLOTSTRIDE; i += 256)
            ws[SLOT0 + i] = 0.0f;
    }
    const int b   = blockIdx.x >> 5;           // 32 segments per batch
    const int seg = blockIdx.x & 31;
    const int perseg = (H_ * W_) / 32;         // 7360 floats
    const float4* p = (const float4*)(tgt + (size_t)b * (H_ * W_) + (size_t)seg * perseg);
    const int n4 = perseg / 4;                 // 1840
    float m = 0.0f;
    for (int i = threadIdx.x; i < n4; i += 256) {
        float4 v = p[i];
        m = fmaxf(m, fmaxf(fmaxf(v.x, v.y), fmaxf(v.z, v.w)));
    }
    #pragma unroll
    for (int off = 32; off; off >>= 1)
        m = fmaxf(m, __shfl_down(m, off, 64));
    __shared__ float sm[4];
    const int lane = threadIdx.x & 63, wv = threadIdx.x >> 6;
    if (lane == 0) sm[wv] = m;
    __syncthreads();
    if (threadIdx.x == 0) {
        m = fmaxf(fmaxf(sm[0], sm[1]), fmaxf(sm[2], sm[3]));
        atomicMax((int*)ws + b, __float_as_int(m));   // inputs >= 0
    }
}

__global__ __launch_bounds__(256) void k_ssim(const float* __restrict__ X,
                                              const float* __restrict__ Y,
                                              float* __restrict__ ws) {
    const int sx   = blockIdx.x;               // column stripe
    const int w    = threadIdx.x >> 6;         // wave within block
    const int lane = threadIdx.x & 63;
    const int b    = blockIdx.z;
    const int chunkIdx = blockIdx.y * 4 + w;   // 0..47 (46 valid)
    const int r0   = chunkIdx * CHUNK;
    const int c    = sx * 64 + lane;
    const int outRows = min(CHUNK, OH - r0);   // <=0 for invalid chunks
    const bool colOK = (c < OW);

    const float dr  = ws[b];
    float C1 = 0.01f * dr; C1 *= C1;
    float C2 = 0.03f * dr; C2 *= C2;
    const float c1s = C1 * 2401.0f;            // C1 * 49^2 (scaled-domain constants)
    const float c2s = C2 * 2401.0f;
    const float covn2 = 2.0f * (49.0f / 48.0f);
    const float covn  = 49.0f / 48.0f;

    const float* xb = X + (size_t)b * (H_ * W_);
    const float* yb = Y + (size_t)b * (H_ * W_);

    float acc = 0.0f;

    if (colOK && outRows > 0) {
        float rx[7], ry[7], rxx[7], ryy[7], rxy[7];
        float tx = 0, ty = 0, txx = 0, tyy = 0, txy = 0;

        #pragma unroll
        for (int p = 0; p < 6; ++p) {          // prime 6 halo rows
            const float* xr = xb + (size_t)(r0 + p) * W_ + c;
            const float* yr = yb + (size_t)(r0 + p) * W_ + c;
            float hx = 0, hy = 0, hxx = 0, hyy = 0, hxy = 0;
            #pragma unroll
            for (int k = 0; k < 7; ++k) {
                float xv = xr[k], yv = yr[k];
                hx += xv; hy += yv;
                hxx = fmaf(xv, xv, hxx);
                hyy = fmaf(yv, yv, hyy);
                hxy = fmaf(xv, yv, hxy);
            }
            rx[p] = hx; ry[p] = hy; rxx[p] = hxx; ryy[p] = hyy; rxy[p] = hxy;
            tx += hx; ty += hy; txx += hxx; tyy += hyy; txy += hxy;
        }

        for (int ii = 0; ii < outRows; ii += 7) {
            #pragma unroll
            for (int p = 0; p < 7; ++p) {      // ring slots compile-time
                const int i = ii + p;
                if (i >= outRows) break;       // wave-uniform
                const float* xr = xb + (size_t)(r0 + i + 6) * W_ + c;
                const float* yr = yb + (size_t)(r0 + i + 6) * W_ + c;
                float hx = 0, hy = 0, hxx = 0, hyy = 0, hxy = 0;
                #pragma unroll
                for (int k = 0; k < 7; ++k) {
                    float xv = xr[k], yv = yr[k];
                    hx += xv; hy += yv;
                    hxx = fmaf(xv, xv, hxx);
                    hyy = fmaf(yv, yv, hyy);
                    hxy = fmaf(xv, yv, hxy);
                }
                tx += hx; ty += hy; txx += hxx; tyy += hyy; txy += hxy;

                // scaled-domain SSIM: all u* scales cancel in the ratio
                const float pxy = tx * ty;
                const float A1  = fmaf(pxy, 2.0f, c1s);            // 2*tx*ty + C1*49^2
                const float s2  = fmaf(tx, tx, ty * ty);           // tx^2 + ty^2
                const float B1  = s2 + c1s;
                const float mxy = fmaf(49.0f, txy, -pxy);          // 49*txy - tx*ty
                const float A2  = fmaf(covn2, mxy, c2s);
                const float vs  = fmaf(49.0f, txx + tyy, -s2);     // 49*(txx+tyy) - (tx^2+ty^2)
                const float B2  = fmaf(covn, vs, c2s);
                acc = fmaf(A1 * A2, __builtin_amdgcn_rcpf(B1 * B2), acc);

                tx -= rx[p]; ty -= ry[p]; txx -= rxx[p]; tyy -= ryy[p]; txy -= rxy[p];
                const int sn = (p + 6) % 7;
                rx[sn] = hx; ry[sn] = hy; rxx[sn] = hxx; ryy[sn] = hyy; rxy[sn] = hxy;
            }
        }
    }

    // wave reduce, then LDS reduce across the 4 waves, ONE atomic per block
    #pragma unroll
    for (int off = 32; off; off >>= 1)
        acc += __shfl_down(acc, off, 64);
    __shared__ float sm[4];
    if (lane == 0) sm[w] = acc;
    __syncthreads();
    if (threadIdx.x == 0) {
        const float s = (sm[0] + sm[1]) + (sm[2] + sm[3]);
        const int blk = (blockIdx.z * NCY + blockIdx.y) * NSTRIPE + blockIdx.x;
        atomicAdd(ws + SLOT0 + (blk & 63) * SLOTSTRIDE, s);   // 64 independent cachelines
    }
}

__global__ __launch_bounds__(64) void k_fin(const float* __restrict__ ws,
                                            float* __restrict__ out) {
    float v = ws[SLOT0 + threadIdx.x * SLOTSTRIDE];
    #pragma unroll
    for (int off = 32; off; off >>= 1)
        v += __shfl_down(v, off, 64);
    if (threadIdx.x == 0)
        out[0] = 1.0f - v * (1.0f / (32.0f * 634.0f * 362.0f));
}

extern "C" void kernel_launch(void* const* d_in, const int* in_sizes, int n_in,
                              void* d_out, int out_size, void* d_ws, size_t ws_size,
                              hipStream_t stream) {
    const float* X = (const float*)d_in[0];   // 'output'
    const float* Y = (const float*)d_in[1];   // 'target'
    float* ws = (float*)d_ws;

    k_max<<<dim3(1024), dim3(256), 0, stream>>>(Y, ws);
    k_ssim<<<dim3(NSTRIPE, NCY, B_), dim3(256), 0, stream>>>(X, Y, ws);
    k_fin<<<dim3(1), dim3(64), 0, stream>>>(ws, (float*)d_out);
}